// Round 13
// baseline (661.226 us; speedup 1.0000x reference)
//
#include <hip/hip_runtime.h>
#include <hip/hip_fp16.h>

#define HDIM 128
#define BN_EPS 1e-5f

typedef _Float16 f16x8 __attribute__((ext_vector_type(8)));
typedef _Float16 f16x4 __attribute__((ext_vector_type(4)));
typedef float    f32x4 __attribute__((ext_vector_type(4)));

// ---- fp16 helpers ----
__device__ inline float4 ld_h4(const _Float16* p) {
    f16x4 r = *(const f16x4*)p;
    return make_float4((float)r.x, (float)r.y, (float)r.z, (float)r.w);
}

__device__ inline void st_h4(_Float16* p, float4 v) {
    f16x4 o = { (_Float16)v.x, (_Float16)v.y, (_Float16)v.z, (_Float16)v.w };
    *(f16x4*)p = o;
}

// ================= prologue: degree, dinv, CSR build =================

__global__ void k_zero2(int* __restrict__ a, int* __restrict__ b, int n) {
    int i = blockIdx.x * blockDim.x + threadIdx.x;
    if (i < n) { a[i] = 0; b[i] = 0; }
}

__global__ void k_deg_accum(const int* __restrict__ dst, int* __restrict__ deg, int e) {
    int i = blockIdx.x * blockDim.x + threadIdx.x;
    if (i < e) atomicAdd(&deg[dst[i]], 1);
}

__global__ void k_dinv(const int* __restrict__ deg, float* __restrict__ dinv, int n) {
    int i = blockIdx.x * blockDim.x + threadIdx.x;
    if (i < n) dinv[i] = rsqrtf((float)deg[i] + 1.0f);   // +1 self-loop
}

__global__ void k_scan1(const int* __restrict__ deg, int* __restrict__ rs,
                        int* __restrict__ blk, int n) {
    __shared__ int s[256];
    int i = blockIdx.x * 256 + threadIdx.x;
    int v = (i < n) ? deg[i] : 0;
    s[threadIdx.x] = v;
    __syncthreads();
    for (int off = 1; off < 256; off <<= 1) {
        int t = (threadIdx.x >= off) ? s[threadIdx.x - off] : 0;
        __syncthreads();
        s[threadIdx.x] += t;
        __syncthreads();
    }
    if (i < n) rs[i] = s[threadIdx.x] - v;               // exclusive
    if (threadIdx.x == 255) blk[blockIdx.x] = s[255];
}

__global__ void k_scan2(int* __restrict__ blk, int nb) {
    __shared__ int s[256];
    int t = threadIdx.x;
    int v = (t < nb) ? blk[t] : 0;
    s[t] = v;
    __syncthreads();
    for (int off = 1; off < 256; off <<= 1) {
        int u = (t >= off) ? s[t - off] : 0;
        __syncthreads();
        s[t] += u;
        __syncthreads();
    }
    if (t < nb) blk[t] = s[t] - v;                       // exclusive
}

__global__ void k_scan3(int* __restrict__ rs, const int* __restrict__ blk, int n) {
    int i = blockIdx.x * 256 + threadIdx.x;
    if (i < n) rs[i] += blk[blockIdx.x];
}

__global__ void k_fill(const int* __restrict__ src, const int* __restrict__ dst,
                       const int* __restrict__ rs, int* __restrict__ cur,
                       int* __restrict__ csr, int e) {
    int i = blockIdx.x * blockDim.x + threadIdx.x;
    if (i >= e) return;
    int d = dst[i];
    int pos = rs[d] + atomicAdd(&cur[d], 1);
    csr[pos] = src[i];
}

__global__ void k_bounds(const int* __restrict__ batch, int* __restrict__ bnd,
                         int n, int g) {
    int i = blockIdx.x * blockDim.x + threadIdx.x;
    if (i >= n) return;
    int b = batch[i];
    if (i == 0) {
        for (int q = 0; q <= b; ++q) bnd[q] = 0;
    } else {
        int p = batch[i - 1];
        for (int q = p + 1; q <= b; ++q) bnd[q] = i;
    }
    if (i == n - 1) {
        for (int q = b + 1; q <= g; ++q) bnd[q] = n;
    }
}

// ================= W convert: wt[col][k] = (fp16) W[k][col] =================
__global__ __launch_bounds__(256) void k_wconv(const float* __restrict__ W,
                                               _Float16* __restrict__ wt) {
    int idx = blockIdx.x * 256 + threadIdx.x;    // 16384
    int k = idx >> 7, c = idx & 127;
    wt[(size_t)c * HDIM + k] = (_Float16)W[(size_t)k * HDIM + c];
}

// ================= layer-0 GEMM (K = F_IN = 11, fp32 VALU) =================
__global__ __launch_bounds__(256) void k_gemm0(
    const float* __restrict__ x, const float* __restrict__ W,
    const float* __restrict__ dinv, _Float16* __restrict__ hs, int n, int fin) {
    int row = blockIdx.x * 2 + (threadIdx.x >> 7);
    int f = threadIdx.x & 127;
    if (row >= n) return;
    float acc = 0.0f;
    for (int k = 0; k < fin; ++k)
        acc += x[row * fin + k] * W[k * HDIM + f];
    hs[(size_t)row * HDIM + f] = (_Float16)(acc * dinv[row]);
}

// ================= MFMA GEMM: hs = (x @ W) * dinv, fp16 in / fp32 acc =================
// A = Wt tile (16 out-cols x 32 k), B = xh tile (16 x-rows, contiguous k).
// D frag: col(lane&15)=x-row, row((lane>>4)*4+r)=4 consecutive out-features -> 8B stores.
__global__ __launch_bounds__(256) void k_gemm_mfma(
    const _Float16* __restrict__ xh, const _Float16* __restrict__ wt,
    const float* __restrict__ dinv, _Float16* __restrict__ hs, int n) {
    int wid  = threadIdx.x >> 6;                 // wave 0..3
    int lane = threadIdx.x & 63;
    int xr   = blockIdx.x * 64 + wid * 16 + (lane & 15);
    int kc   = (lane >> 4) * 8;                  // k-chunk base within 32

    f32x4 acc[8];
    #pragma unroll
    for (int t = 0; t < 8; ++t) acc[t] = (f32x4){0.f, 0.f, 0.f, 0.f};

    #pragma unroll
    for (int kb = 0; kb < HDIM; kb += 32) {
        f16x8 bfrag = {};
        if (xr < n) bfrag = *(const f16x8*)(xh + (size_t)xr * HDIM + kb + kc);
        #pragma unroll
        for (int t = 0; t < 8; ++t) {
            f16x8 afrag = *(const f16x8*)(wt + (size_t)(t * 16 + (lane & 15)) * HDIM + kb + kc);
            acc[t] = __builtin_amdgcn_mfma_f32_16x16x32_f16(afrag, bfrag, acc[t], 0, 0, 0);
        }
    }

    if (xr >= n) return;
    float di = dinv[xr];
    #pragma unroll
    for (int t = 0; t < 8; ++t) {
        int c0 = t * 16 + (lane >> 4) * 4;       // 4 consecutive out-features
        f16x4 o = { (_Float16)(acc[t][0] * di), (_Float16)(acc[t][1] * di),
                    (_Float16)(acc[t][2] * di), (_Float16)(acc[t][3] * di) };
        *(f16x4*)(hs + (size_t)xr * HDIM + c0) = o;
    }
}

// ========== fused CSR gather + bias + BN + ReLU + residual, XCD-sliced ==========
// slice = blockIdx.x & 7 (round-robin -> per-XCD L2 keeps a 1.6 MB hs slice resident)
// 4 lanes per node, 4 halfs (8 B) each = 16 features per slice; 64 nodes/block
__global__ __launch_bounds__(256) void k_agg(
    const int* __restrict__ rs, const int* __restrict__ deg,
    const int* __restrict__ csr, const _Float16* __restrict__ hs,
    const float* __restrict__ dinv, const float* __restrict__ bias,
    const float* __restrict__ gamma, const float* __restrict__ beta,
    const float* __restrict__ mean, const float* __restrict__ var,
    const float* __restrict__ xold, float* __restrict__ xnew,
    _Float16* __restrict__ xh, int n, int use_res) {
    int slice = blockIdx.x & 7;
    int node  = (blockIdx.x >> 3) * 64 + (threadIdx.x >> 2);
    if (node >= n) return;
    int f = slice * 16 + (threadIdx.x & 3) * 4;  // feature offset (4 floats)
    size_t base = (size_t)node * HDIM + f;

    float4 a0 = ld_h4(hs + base);                // self-loop term
    float4 a1 = make_float4(0.f, 0.f, 0.f, 0.f);
    float4 a2 = make_float4(0.f, 0.f, 0.f, 0.f);
    float4 a3 = make_float4(0.f, 0.f, 0.f, 0.f);
    int start = rs[node];
    int d = deg[node];
    int j = 0;
    for (; j + 4 <= d; j += 4) {
        int s0 = csr[start + j];
        int s1 = csr[start + j + 1];
        int s2 = csr[start + j + 2];
        int s3 = csr[start + j + 3];
        float4 v0 = ld_h4(hs + (size_t)s0 * HDIM + f);
        float4 v1 = ld_h4(hs + (size_t)s1 * HDIM + f);
        float4 v2 = ld_h4(hs + (size_t)s2 * HDIM + f);
        float4 v3 = ld_h4(hs + (size_t)s3 * HDIM + f);
        a0.x += v0.x; a0.y += v0.y; a0.z += v0.z; a0.w += v0.w;
        a1.x += v1.x; a1.y += v1.y; a1.z += v1.z; a1.w += v1.w;
        a2.x += v2.x; a2.y += v2.y; a2.z += v2.z; a2.w += v2.w;
        a3.x += v3.x; a3.y += v3.y; a3.z += v3.z; a3.w += v3.w;
    }
    for (; j < d; ++j) {
        int s0 = csr[start + j];
        float4 v0 = ld_h4(hs + (size_t)s0 * HDIM + f);
        a0.x += v0.x; a0.y += v0.y; a0.z += v0.z; a0.w += v0.w;
    }
    float4 acc;
    acc.x = (a0.x + a1.x) + (a2.x + a3.x);
    acc.y = (a0.y + a1.y) + (a2.y + a3.y);
    acc.z = (a0.z + a1.z) + (a2.z + a3.z);
    acc.w = (a0.w + a1.w) + (a2.w + a3.w);

    float di = dinv[node];
    float4 bv = *(const float4*)(bias + f);
    float4 gv = *(const float4*)(gamma + f);
    float4 be = *(const float4*)(beta + f);
    float4 mv = *(const float4*)(mean + f);
    float4 vv = *(const float4*)(var + f);
    float4 o;
    o.x = fmaxf((di * acc.x + bv.x - mv.x) * rsqrtf(vv.x + BN_EPS) * gv.x + be.x, 0.f);
    o.y = fmaxf((di * acc.y + bv.y - mv.y) * rsqrtf(vv.y + BN_EPS) * gv.y + be.y, 0.f);
    o.z = fmaxf((di * acc.z + bv.z - mv.z) * rsqrtf(vv.z + BN_EPS) * gv.z + be.z, 0.f);
    o.w = fmaxf((di * acc.w + bv.w - mv.w) * rsqrtf(vv.w + BN_EPS) * gv.w + be.w, 0.f);
    if (use_res) {
        float4 xo = *(const float4*)(xold + base);
        o.x += xo.x; o.y += xo.y; o.z += xo.z; o.w += xo.w;
    }
    *(float4*)(xnew + base) = o;
    st_h4(xh + base, o);                         // fp16 shadow for next MFMA GEMM
}

// ================= segmented mean-pool (no atomics; batch sorted) =================
__global__ __launch_bounds__(256) void k_pool_seg(
    const float* __restrict__ x, const int* __restrict__ bnd,
    float* __restrict__ pooled, int g) {
    int gid = blockIdx.x * 8 + (threadIdx.x >> 5);
    if (gid >= g) return;
    int f4 = (threadIdx.x & 31) * 4;
    int s = bnd[gid], t = bnd[gid + 1];
    float4 a0 = make_float4(0.f, 0.f, 0.f, 0.f);
    float4 a1 = make_float4(0.f, 0.f, 0.f, 0.f);
    int r = s;
    for (; r + 2 <= t; r += 2) {
        float4 v0 = *(const float4*)(x + (size_t)r * HDIM + f4);
        float4 v1 = *(const float4*)(x + (size_t)(r + 1) * HDIM + f4);
        a0.x += v0.x; a0.y += v0.y; a0.z += v0.z; a0.w += v0.w;
        a1.x += v1.x; a1.y += v1.y; a1.z += v1.z; a1.w += v1.w;
    }
    if (r < t) {
        float4 v0 = *(const float4*)(x + (size_t)r * HDIM + f4);
        a0.x += v0.x; a0.y += v0.y; a0.z += v0.z; a0.w += v0.w;
    }
    float inv = (t > s) ? 1.0f / (float)(t - s) : 0.0f;
    float4 o = make_float4((a0.x + a1.x) * inv, (a0.y + a1.y) * inv,
                           (a0.z + a1.z) * inv, (a0.w + a1.w) * inv);
    *(float4*)(pooled + (size_t)gid * HDIM + f4) = o;
}

// ================= head MLP =================
__global__ __launch_bounds__(64) void k_head(
    const float* __restrict__ pooled,
    const float* __restrict__ w1, const float* __restrict__ b1,
    const float* __restrict__ w2, const float* __restrict__ b2,
    float* __restrict__ out) {
    __shared__ float p[HDIM];
    int g = blockIdx.x;
    int t = threadIdx.x;
    p[t]      = pooled[(size_t)g * HDIM + t];
    p[t + 64] = pooled[(size_t)g * HDIM + 64 + t];
    __syncthreads();
    float h = b1[t];
    #pragma unroll 4
    for (int k = 0; k < HDIM; ++k)
        h += p[k] * w1[k * 64 + t];
    h = fmaxf(h, 0.f);
    float part = h * w2[t];
    #pragma unroll
    for (int off = 32; off > 0; off >>= 1)
        part += __shfl_down(part, off);
    if (t == 0) out[g] = part + b2[0];
}

extern "C" void kernel_launch(void* const* d_in, const int* in_sizes, int n_in,
                              void* d_out, int out_size, void* d_ws, size_t ws_size,
                              hipStream_t stream) {
    const float* x0   = (const float*)d_in[0];
    const int*   eidx = (const int*)  d_in[1];
    const int*   batch= (const int*)  d_in[2];
    const float* W0   = (const float*)d_in[3];
    const float* b0   = (const float*)d_in[4];
    const float* Ws   = (const float*)d_in[5];
    const float* bs   = (const float*)d_in[6];
    const float* gam  = (const float*)d_in[7];
    const float* bet  = (const float*)d_in[8];
    const float* mean = (const float*)d_in[9];
    const float* var  = (const float*)d_in[10];
    const float* w1   = (const float*)d_in[11];
    const float* b1   = (const float*)d_in[12];
    const float* w2   = (const float*)d_in[13];
    const float* b2   = (const float*)d_in[14];

    const int FIN = 11;
    int n = in_sizes[0] / FIN;      // 50000
    int e = in_sizes[1] / 2;        // 600000
    int g = out_size;               // 2048
    int nb = (n + 255) / 256;       // scan blocks

    const int* src = eidx;
    const int* dst = eidx + e;

    // ---- workspace carve-up (keep 16B alignment everywhere) ----
    char* ws = (char*)d_ws;
    size_t nal = ((size_t)n + 255) & ~(size_t)255;
    int*      deg   = (int*)ws;                    ws += nal * 4;
    int*      cur   = (int*)ws;                    ws += nal * 4;
    int*      rs    = (int*)ws;                    ws += nal * 4;
    int*      blk   = (int*)ws;                    ws += 256 * 4;
    int*      bnd   = (int*)ws;                    ws += ((size_t)g + 64) / 64 * 64 * 4;
    int*      csr   = (int*)ws;                    ws += ((size_t)e + 63) / 64 * 64 * 4;
    float*    dinv  = (float*)ws;                  ws += nal * 4;
    _Float16* wt    = (_Float16*)ws;               ws += (size_t)HDIM * HDIM * 2;
    float*    bufA  = (float*)ws;                  ws += (size_t)n * HDIM * 4;   // x fp32
    _Float16* bufH  = (_Float16*)ws;               ws += (size_t)n * HDIM * 2;   // hs fp16
    _Float16* xh    = (_Float16*)ws;               ws += (size_t)n * HDIM * 2;   // x fp16 shadow
    float*    pooled= (float*)ws;

    // ---- prologue: degree, dinv, CSR, graph bounds ----
    k_zero2<<<nb, 256, 0, stream>>>(deg, cur, n);
    k_deg_accum<<<(e + 255) / 256, 256, 0, stream>>>(dst, deg, e);
    k_dinv<<<nb, 256, 0, stream>>>(deg, dinv, n);
    k_scan1<<<nb, 256, 0, stream>>>(deg, rs, blk, n);
    k_scan2<<<1, 256, 0, stream>>>(blk, nb);
    k_scan3<<<nb, 256, 0, stream>>>(rs, blk, n);
    k_fill<<<(e + 255) / 256, 256, 0, stream>>>(src, dst, rs, cur, csr, e);
    k_bounds<<<nb, 256, 0, stream>>>(batch, bnd, n, g);

    int aggGrid = ((n + 63) / 64) * 8;             // slices x node-blocks

    // ---- 5 GCN layers: x in bufA (fp32) + xh (fp16), hs in bufH (fp16) ----
    for (int i = 0; i < 5; ++i) {
        const float* xin = (i == 0) ? x0 : bufA;
        const float* bias = (i == 0) ? b0 : bs + (size_t)(i - 1) * HDIM;
        if (i == 0) {
            k_gemm0<<<(n + 1) / 2, 256, 0, stream>>>(x0, W0, dinv, bufH, n, FIN);
        } else {
            const float* W = Ws + (size_t)(i - 1) * HDIM * HDIM;
            k_wconv<<<64, 256, 0, stream>>>(W, wt);
            k_gemm_mfma<<<(n + 63) / 64, 256, 0, stream>>>(xh, wt, dinv, bufH, n);
        }
        k_agg<<<aggGrid, 256, 0, stream>>>(
            rs, deg, csr, bufH, dinv, bias,
            gam + i * HDIM, bet + i * HDIM, mean + i * HDIM, var + i * HDIM,
            xin, bufA, xh, n, (i > 0) ? 1 : 0);
    }

    // ---- segmented mean pool + head ----
    k_pool_seg<<<(g + 7) / 8, 256, 0, stream>>>(bufA, bnd, pooled, g);
    k_head<<<g, 64, 0, stream>>>(pooled, w1, b1, w2, b2, (float*)d_out);
}

// Round 17
// 480.236 us; speedup vs baseline: 1.3769x; 1.3769x over previous
//
#include <hip/hip_runtime.h>
#include <hip/hip_fp16.h>

#define HDIM 128
#define BN_EPS 1e-5f

typedef _Float16 f16x8 __attribute__((ext_vector_type(8)));
typedef _Float16 f16x4 __attribute__((ext_vector_type(4)));
typedef float    f32x4 __attribute__((ext_vector_type(4)));

// ---- fp16 helpers ----
__device__ inline float4 ld_h4(const _Float16* p) {
    f16x4 r = *(const f16x4*)p;
    return make_float4((float)r.x, (float)r.y, (float)r.z, (float)r.w);
}

__device__ inline void st_h4(_Float16* p, float4 v) {
    f16x4 o = { (_Float16)v.x, (_Float16)v.y, (_Float16)v.z, (_Float16)v.w };
    *(f16x4*)p = o;
}

// ================= prologue: degree, dinv, CSR build =================

__global__ void k_zero2(int* __restrict__ a, int* __restrict__ b, int n) {
    int i = blockIdx.x * blockDim.x + threadIdx.x;
    if (i < n) { a[i] = 0; b[i] = 0; }
}

__global__ void k_deg_accum(const int* __restrict__ dst, int* __restrict__ deg, int e) {
    int i = blockIdx.x * blockDim.x + threadIdx.x;
    if (i < e) atomicAdd(&deg[dst[i]], 1);
}

__global__ void k_dinv(const int* __restrict__ deg, float* __restrict__ dinv, int n) {
    int i = blockIdx.x * blockDim.x + threadIdx.x;
    if (i < n) dinv[i] = rsqrtf((float)deg[i] + 1.0f);   // +1 self-loop
}

__global__ void k_scan1(const int* __restrict__ deg, int* __restrict__ rs,
                        int* __restrict__ blk, int n) {
    __shared__ int s[256];
    int i = blockIdx.x * 256 + threadIdx.x;
    int v = (i < n) ? deg[i] : 0;
    s[threadIdx.x] = v;
    __syncthreads();
    for (int off = 1; off < 256; off <<= 1) {
        int t = (threadIdx.x >= off) ? s[threadIdx.x - off] : 0;
        __syncthreads();
        s[threadIdx.x] += t;
        __syncthreads();
    }
    if (i < n) rs[i] = s[threadIdx.x] - v;               // exclusive
    if (threadIdx.x == 255) blk[blockIdx.x] = s[255];
}

__global__ void k_scan2(int* __restrict__ blk, int nb) {
    __shared__ int s[256];
    int t = threadIdx.x;
    int v = (t < nb) ? blk[t] : 0;
    s[t] = v;
    __syncthreads();
    for (int off = 1; off < 256; off <<= 1) {
        int u = (t >= off) ? s[t - off] : 0;
        __syncthreads();
        s[t] += u;
        __syncthreads();
    }
    if (t < nb) blk[t] = s[t] - v;                       // exclusive
}

__global__ void k_scan3(int* __restrict__ rs, const int* __restrict__ blk, int n) {
    int i = blockIdx.x * 256 + threadIdx.x;
    if (i < n) rs[i] += blk[blockIdx.x];
}

__global__ void k_fill(const int* __restrict__ src, const int* __restrict__ dst,
                       const int* __restrict__ rs, int* __restrict__ cur,
                       int* __restrict__ csr, int e) {
    int i = blockIdx.x * blockDim.x + threadIdx.x;
    if (i >= e) return;
    int d = dst[i];
    int pos = rs[d] + atomicAdd(&cur[d], 1);
    csr[pos] = src[i];
}

__global__ void k_bounds(const int* __restrict__ batch, int* __restrict__ bnd,
                         int n, int g) {
    int i = blockIdx.x * blockDim.x + threadIdx.x;
    if (i >= n) return;
    int b = batch[i];
    if (i == 0) {
        for (int q = 0; q <= b; ++q) bnd[q] = 0;
    } else {
        int p = batch[i - 1];
        for (int q = p + 1; q <= b; ++q) bnd[q] = i;
    }
    if (i == n - 1) {
        for (int q = b + 1; q <= g; ++q) bnd[q] = n;
    }
}

// ======== W convert (ALL 4 layers in one launch): wt[l][c][k] = (fp16) W[l][k][c] ========
__global__ __launch_bounds__(256) void k_wconv_all(const float* __restrict__ Ws,
                                                   _Float16* __restrict__ wt, int nmats) {
    int idx = blockIdx.x * 256 + threadIdx.x;          // nmats * 16384
    if (idx >= nmats * HDIM * HDIM) return;
    int l = idx >> 14, rem = idx & 16383;
    int k = rem >> 7, c = rem & 127;
    wt[(size_t)l * HDIM * HDIM + (size_t)c * HDIM + k] =
        (_Float16)Ws[(size_t)l * HDIM * HDIM + (size_t)k * HDIM + c];
}

// ================= layer-0 GEMM (K = F_IN = 11, fp32 VALU) =================
__global__ __launch_bounds__(256) void k_gemm0(
    const float* __restrict__ x, const float* __restrict__ W,
    const float* __restrict__ dinv, _Float16* __restrict__ hs, int n, int fin) {
    int row = blockIdx.x * 2 + (threadIdx.x >> 7);
    int f = threadIdx.x & 127;
    if (row >= n) return;
    float acc = 0.0f;
    for (int k = 0; k < fin; ++k)
        acc += x[row * fin + k] * W[k * HDIM + f];
    hs[(size_t)row * HDIM + f] = (_Float16)(acc * dinv[row]);
}

// ================= MFMA GEMM: hs = (x @ W) * dinv, fp16 in / fp32 acc =================
// A = Wt tile (16 out-cols x 32 k), B = xh tile (16 x-rows, contiguous k).
// D frag: col(lane&15)=x-row, row((lane>>4)*4+r)=4 consecutive out-features -> 8B stores.
__global__ __launch_bounds__(256) void k_gemm_mfma(
    const _Float16* __restrict__ xh, const _Float16* __restrict__ wt,
    const float* __restrict__ dinv, _Float16* __restrict__ hs, int n) {
    int wid  = threadIdx.x >> 6;                 // wave 0..3
    int lane = threadIdx.x & 63;
    int xr   = blockIdx.x * 64 + wid * 16 + (lane & 15);
    int kc   = (lane >> 4) * 8;                  // k-chunk base within 32

    f32x4 acc[8];
    #pragma unroll
    for (int t = 0; t < 8; ++t) acc[t] = (f32x4){0.f, 0.f, 0.f, 0.f};

    #pragma unroll
    for (int kb = 0; kb < HDIM; kb += 32) {
        f16x8 bfrag = {};
        if (xr < n) bfrag = *(const f16x8*)(xh + (size_t)xr * HDIM + kb + kc);
        #pragma unroll
        for (int t = 0; t < 8; ++t) {
            f16x8 afrag = *(const f16x8*)(wt + (size_t)(t * 16 + (lane & 15)) * HDIM + kb + kc);
            acc[t] = __builtin_amdgcn_mfma_f32_16x16x32_f16(afrag, bfrag, acc[t], 0, 0, 0);
        }
    }

    if (xr >= n) return;
    float di = dinv[xr];
    #pragma unroll
    for (int t = 0; t < 8; ++t) {
        int c0 = t * 16 + (lane >> 4) * 4;       // 4 consecutive out-features
        f16x4 o = { (_Float16)(acc[t][0] * di), (_Float16)(acc[t][1] * di),
                    (_Float16)(acc[t][2] * di), (_Float16)(acc[t][3] * di) };
        *(f16x4*)(hs + (size_t)xr * HDIM + c0) = o;
    }
}

// ========== fused CSR gather (fp16, full row) + bias + BN + ReLU + residual ==========
// 32 lanes per node, 4 halfs (8 B) each -> full 256 B row per node; unroll-4 MLP
__global__ __launch_bounds__(256) void k_agg(
    const int* __restrict__ rs, const int* __restrict__ deg,
    const int* __restrict__ csr, const _Float16* __restrict__ hs,
    const float* __restrict__ dinv, const float* __restrict__ bias,
    const float* __restrict__ gamma, const float* __restrict__ beta,
    const float* __restrict__ mean, const float* __restrict__ var,
    const float* __restrict__ xold, float* __restrict__ xnew,
    _Float16* __restrict__ xh, int n, int use_res) {
    int node = blockIdx.x * 8 + (threadIdx.x >> 5);
    if (node >= n) return;
    int f4 = (threadIdx.x & 31) * 4;
    size_t base = (size_t)node * HDIM + f4;

    float4 a0 = ld_h4(hs + base);                // self-loop term
    float4 a1 = make_float4(0.f, 0.f, 0.f, 0.f);
    float4 a2 = make_float4(0.f, 0.f, 0.f, 0.f);
    float4 a3 = make_float4(0.f, 0.f, 0.f, 0.f);
    int start = rs[node];
    int d = deg[node];
    int j = 0;
    for (; j + 4 <= d; j += 4) {
        int s0 = csr[start + j];
        int s1 = csr[start + j + 1];
        int s2 = csr[start + j + 2];
        int s3 = csr[start + j + 3];
        float4 v0 = ld_h4(hs + (size_t)s0 * HDIM + f4);
        float4 v1 = ld_h4(hs + (size_t)s1 * HDIM + f4);
        float4 v2 = ld_h4(hs + (size_t)s2 * HDIM + f4);
        float4 v3 = ld_h4(hs + (size_t)s3 * HDIM + f4);
        a0.x += v0.x; a0.y += v0.y; a0.z += v0.z; a0.w += v0.w;
        a1.x += v1.x; a1.y += v1.y; a1.z += v1.z; a1.w += v1.w;
        a2.x += v2.x; a2.y += v2.y; a2.z += v2.z; a2.w += v2.w;
        a3.x += v3.x; a3.y += v3.y; a3.z += v3.z; a3.w += v3.w;
    }
    for (; j < d; ++j) {
        int s0 = csr[start + j];
        float4 v0 = ld_h4(hs + (size_t)s0 * HDIM + f4);
        a0.x += v0.x; a0.y += v0.y; a0.z += v0.z; a0.w += v0.w;
    }
    float4 acc;
    acc.x = (a0.x + a1.x) + (a2.x + a3.x);
    acc.y = (a0.y + a1.y) + (a2.y + a3.y);
    acc.z = (a0.z + a1.z) + (a2.z + a3.z);
    acc.w = (a0.w + a1.w) + (a2.w + a3.w);

    float di = dinv[node];
    float4 bv = *(const float4*)(bias + f4);
    float4 gv = *(const float4*)(gamma + f4);
    float4 be = *(const float4*)(beta + f4);
    float4 mv = *(const float4*)(mean + f4);
    float4 vv = *(const float4*)(var + f4);
    float4 o;
    o.x = fmaxf((di * acc.x + bv.x - mv.x) * rsqrtf(vv.x + BN_EPS) * gv.x + be.x, 0.f);
    o.y = fmaxf((di * acc.y + bv.y - mv.y) * rsqrtf(vv.y + BN_EPS) * gv.y + be.y, 0.f);
    o.z = fmaxf((di * acc.z + bv.z - mv.z) * rsqrtf(vv.z + BN_EPS) * gv.z + be.z, 0.f);
    o.w = fmaxf((di * acc.w + bv.w - mv.w) * rsqrtf(vv.w + BN_EPS) * gv.w + be.w, 0.f);
    if (use_res) {
        float4 xo = *(const float4*)(xold + base);
        o.x += xo.x; o.y += xo.y; o.z += xo.z; o.w += xo.w;
    }
    *(float4*)(xnew + base) = o;
    st_h4(xh + base, o);                         // fp16 shadow for next MFMA GEMM
}

// ================= segmented mean-pool (no atomics; batch sorted) =================
__global__ __launch_bounds__(256) void k_pool_seg(
    const float* __restrict__ x, const int* __restrict__ bnd,
    float* __restrict__ pooled, int g) {
    int gid = blockIdx.x * 8 + (threadIdx.x >> 5);
    if (gid >= g) return;
    int f4 = (threadIdx.x & 31) * 4;
    int s = bnd[gid], t = bnd[gid + 1];
    float4 a0 = make_float4(0.f, 0.f, 0.f, 0.f);
    float4 a1 = make_float4(0.f, 0.f, 0.f, 0.f);
    int r = s;
    for (; r + 2 <= t; r += 2) {
        float4 v0 = *(const float4*)(x + (size_t)r * HDIM + f4);
        float4 v1 = *(const float4*)(x + (size_t)(r + 1) * HDIM + f4);
        a0.x += v0.x; a0.y += v0.y; a0.z += v0.z; a0.w += v0.w;
        a1.x += v1.x; a1.y += v1.y; a1.z += v1.z; a1.w += v1.w;
    }
    if (r < t) {
        float4 v0 = *(const float4*)(x + (size_t)r * HDIM + f4);
        a0.x += v0.x; a0.y += v0.y; a0.z += v0.z; a0.w += v0.w;
    }
    float inv = (t > s) ? 1.0f / (float)(t - s) : 0.0f;
    float4 o = make_float4((a0.x + a1.x) * inv, (a0.y + a1.y) * inv,
                           (a0.z + a1.z) * inv, (a0.w + a1.w) * inv);
    *(float4*)(pooled + (size_t)gid * HDIM + f4) = o;
}

// ================= head MLP =================
__global__ __launch_bounds__(64) void k_head(
    const float* __restrict__ pooled,
    const float* __restrict__ w1, const float* __restrict__ b1,
    const float* __restrict__ w2, const float* __restrict__ b2,
    float* __restrict__ out) {
    __shared__ float p[HDIM];
    int g = blockIdx.x;
    int t = threadIdx.x;
    p[t]      = pooled[(size_t)g * HDIM + t];
    p[t + 64] = pooled[(size_t)g * HDIM + 64 + t];
    __syncthreads();
    float h = b1[t];
    #pragma unroll 4
    for (int k = 0; k < HDIM; ++k)
        h += p[k] * w1[k * 64 + t];
    h = fmaxf(h, 0.f);
    float part = h * w2[t];
    #pragma unroll
    for (int off = 32; off > 0; off >>= 1)
        part += __shfl_down(part, off);
    if (t == 0) out[g] = part + b2[0];
}

extern "C" void kernel_launch(void* const* d_in, const int* in_sizes, int n_in,
                              void* d_out, int out_size, void* d_ws, size_t ws_size,
                              hipStream_t stream) {
    const float* x0   = (const float*)d_in[0];
    const int*   eidx = (const int*)  d_in[1];
    const int*   batch= (const int*)  d_in[2];
    const float* W0   = (const float*)d_in[3];
    const float* b0   = (const float*)d_in[4];
    const float* Ws   = (const float*)d_in[5];
    const float* bs   = (const float*)d_in[6];
    const float* gam  = (const float*)d_in[7];
    const float* bet  = (const float*)d_in[8];
    const float* mean = (const float*)d_in[9];
    const float* var  = (const float*)d_in[10];
    const float* w1   = (const float*)d_in[11];
    const float* b1   = (const float*)d_in[12];
    const float* w2   = (const float*)d_in[13];
    const float* b2   = (const float*)d_in[14];

    const int FIN = 11;
    int n = in_sizes[0] / FIN;      // 50000
    int e = in_sizes[1] / 2;        // 600000
    int g = out_size;               // 2048
    int nb = (n + 255) / 256;       // scan blocks

    const int* src = eidx;
    const int* dst = eidx + e;

    // ---- workspace carve-up (keep 16B alignment everywhere) ----
    char* ws = (char*)d_ws;
    size_t nal = ((size_t)n + 255) & ~(size_t)255;
    int*      deg   = (int*)ws;                    ws += nal * 4;
    int*      cur   = (int*)ws;                    ws += nal * 4;
    int*      rs    = (int*)ws;                    ws += nal * 4;
    int*      blk   = (int*)ws;                    ws += 256 * 4;
    int*      bnd   = (int*)ws;                    ws += ((size_t)g + 64) / 64 * 64 * 4;
    int*      csr   = (int*)ws;                    ws += ((size_t)e + 63) / 64 * 64 * 4;
    float*    dinv  = (float*)ws;                  ws += nal * 4;
    _Float16* wt    = (_Float16*)ws;               ws += (size_t)4 * HDIM * HDIM * 2;
    float*    bufA  = (float*)ws;                  ws += (size_t)n * HDIM * 4;   // x fp32
    _Float16* bufH  = (_Float16*)ws;               ws += (size_t)n * HDIM * 2;   // hs fp16
    _Float16* xh    = (_Float16*)ws;               ws += (size_t)n * HDIM * 2;   // x fp16 shadow
    float*    pooled= (float*)ws;

    // ---- prologue: degree, dinv, CSR, graph bounds, all-layer W convert ----
    k_zero2<<<nb, 256, 0, stream>>>(deg, cur, n);
    k_deg_accum<<<(e + 255) / 256, 256, 0, stream>>>(dst, deg, e);
    k_dinv<<<nb, 256, 0, stream>>>(deg, dinv, n);
    k_scan1<<<nb, 256, 0, stream>>>(deg, rs, blk, n);
    k_scan2<<<1, 256, 0, stream>>>(blk, nb);
    k_scan3<<<nb, 256, 0, stream>>>(rs, blk, n);
    k_fill<<<(e + 255) / 256, 256, 0, stream>>>(src, dst, rs, cur, csr, e);
    k_bounds<<<nb, 256, 0, stream>>>(batch, bnd, n, g);
    k_wconv_all<<<(4 * HDIM * HDIM + 255) / 256, 256, 0, stream>>>(Ws, wt, 4);

    // ---- 5 GCN layers: x in bufA (fp32) + xh (fp16), hs in bufH (fp16) ----
    for (int i = 0; i < 5; ++i) {
        const float* xin = (i == 0) ? x0 : bufA;
        const float* bias = (i == 0) ? b0 : bs + (size_t)(i - 1) * HDIM;
        if (i == 0) {
            k_gemm0<<<(n + 1) / 2, 256, 0, stream>>>(x0, W0, dinv, bufH, n, FIN);
        } else {
            k_gemm_mfma<<<(n + 63) / 64, 256, 0, stream>>>(
                xh, wt + (size_t)(i - 1) * HDIM * HDIM, dinv, bufH, n);
        }
        k_agg<<<(n + 7) / 8, 256, 0, stream>>>(
            rs, deg, csr, bufH, dinv, bias,
            gam + i * HDIM, bet + i * HDIM, mean + i * HDIM, var + i * HDIM,
            xin, bufA, xh, n, (i > 0) ? 1 : 0);
    }

    // ---- segmented mean pool + head ----
    k_pool_seg<<<(g + 7) / 8, 256, 0, stream>>>(bufA, bnd, pooled, g);
    k_head<<<g, 64, 0, stream>>>(pooled, w1, b1, w2, b2, (float*)d_out);
}